// Round 7
// baseline (4300.771 us; speedup 1.0000x reference)
//
#include <hip/hip_runtime.h>
#include <cstdint>
#include <cstddef>

#define DI __device__ __forceinline__

typedef __bf16 bf16_t;
typedef __bf16 bf16x8 __attribute__((ext_vector_type(8)));
typedef float f32x4 __attribute__((ext_vector_type(4)));

static constexpr float SCALE = 0.17677669529663687f;  // 32^-0.5

DI bf16_t f2b(float f) {
  uint32_t u = __builtin_bit_cast(uint32_t, f);
  u += 0x7fffu + ((u >> 16) & 1u);
  return __builtin_bit_cast(bf16_t, (uint16_t)(u >> 16));
}

// ---------------- weight convert f32 -> bf16 ----------------
__global__ __launch_bounds__(256)
void cvtw(const float* __restrict__ in, bf16_t* __restrict__ out, int n) {
  int i = (blockIdx.x * 256 + threadIdx.x) * 4;
  if (i >= n) return;
  float4 v = *(const float4*)(in + i);
  ushort4 o;
  o.x = __builtin_bit_cast(uint16_t, f2b(v.x));
  o.y = __builtin_bit_cast(uint16_t, f2b(v.y));
  o.z = __builtin_bit_cast(uint16_t, f2b(v.z));
  o.w = __builtin_bit_cast(uint16_t, f2b(v.w));
  *(ushort4*)(out + i) = o;
}

// ---------------- rel-pos bias expand: [16][64][64], pad = -1e30 ----------------
__global__ __launch_bounds__(256)
void bias_pre(const float* __restrict__ rel, float* __restrict__ bf) {
  int idx = blockIdx.x * 256 + threadIdx.x;  // 65536
  int head = idx >> 12, t1 = (idx >> 6) & 63, t2 = idx & 63;
  float v = -1e30f;
  if (t1 < 49 && t2 < 49) {
    int i1 = t1 / 7, j1 = t1 - i1 * 7, i2 = t2 / 7, j2 = t2 - i2 * 7;
    v = rel[((i1 - i2 + 6) * 13 + (j1 - j2 + 6)) * 16 + head];
  }
  bf[idx] = v;
}

// ---------------- LayerNorm (+optional shift+window gather) ----------------
template<bool WIN>
__global__ __launch_bounds__(128)
void ln_kernel(const float* __restrict__ in, const float* __restrict__ g,
               const float* __restrict__ be, bf16_t* __restrict__ out)
{
  const int r = blockIdx.x;           // output row (windowed if WIN)
  const int tid = threadIdx.x;
  long srow;
  if (WIN) {
    int bw = r / 49, t = r - bw * 49;
    int b = bw >> 6, w = bw & 63;
    int wh = w >> 3, ww = w & 7;
    int i = t / 7, j = t - i * 7;
    int hs = wh * 7 + i + 3; if (hs >= 56) hs -= 56;
    int wsr = ww * 7 + j + 3; if (wsr >= 56) wsr -= 56;
    srow = (long)b * 3136 + hs * 56 + wsr;
  } else {
    srow = r;
  }
  const float4 v = *(const float4*)(in + srow * 512 + tid * 4);
  float s = v.x + v.y + v.z + v.w;
  float sq = v.x * v.x + v.y * v.y + v.z * v.z + v.w * v.w;
#pragma unroll
  for (int m = 1; m < 64; m <<= 1) { s += __shfl_xor(s, m); sq += __shfl_xor(sq, m); }
  __shared__ float ls[2], lq[2];
  if ((tid & 63) == 0) { ls[tid >> 6] = s; lq[tid >> 6] = sq; }
  __syncthreads();
  s = ls[0] + ls[1]; sq = lq[0] + lq[1];
  const float mean = s * (1.f / 512.f);
  const float rs = rsqrtf(sq * (1.f / 512.f) - mean * mean + 1e-5f);
  const float4 gg = *(const float4*)(g + tid * 4);
  const float4 bb = *(const float4*)(be + tid * 4);
  ushort4 o;
  o.x = __builtin_bit_cast(uint16_t, f2b((v.x - mean) * rs * gg.x + bb.x));
  o.y = __builtin_bit_cast(uint16_t, f2b((v.y - mean) * rs * gg.y + bb.y));
  o.z = __builtin_bit_cast(uint16_t, f2b((v.z - mean) * rs * gg.z + bb.z));
  o.w = __builtin_bit_cast(uint16_t, f2b((v.w - mean) * rs * gg.w + bb.w));
  *(ushort4*)(out + (long)r * 512 + tid * 4) = o;
}

#define MFMA16(a, b, c) __builtin_amdgcn_mfma_f32_16x16x32_bf16((a), (b), (c), 0, 0, 0)

// Common epilogue address/value logic (verified across R3-R6)
template<int EPI>
DI void epi_store(int grow, int gcol, float v, const float* extra,
                  void* out0, void* out1v, void* out2v)
{
  long obase = 0;
  if (EPI == 0) {
    int bwi = grow / 49, t_ = grow - bwi * 49;
    obase = ((long)bwi * 784 + t_) * 32;
  } else if (EPI == 1) {
    int bwi = grow / 49, t_ = grow - bwi * 49;
    int b = bwi >> 6, w = bwi & 63;
    int wh = w >> 3, ww = w & 7;
    int i = t_ / 7, jj = t_ - i * 7;
    int hs = wh * 7 + i + 3; if (hs >= 56) hs -= 56;
    int wsr = ww * 7 + jj + 3; if (wsr >= 56) wsr -= 56;
    obase = ((long)b * 3136 + hs * 56 + wsr) * 512;
  } else if (EPI == 2) {
    obase = (long)grow * 2048;
  } else {
    obase = (long)grow * 512;
  }
  if (EPI == 0) {
    int part = gcol >> 9, head = (gcol >> 5) & 15, d = gcol & 31;
    if (part == 0) v *= SCALE;
    bf16_t* dst = (bf16_t*)(part == 0 ? out0 : (part == 1 ? out1v : out2v));
    dst[obase + (long)head * 1568 + d] = f2b(v);
  } else if (EPI == 1) {
    ((float*)out0)[obase + gcol] = v + extra[obase + gcol];
  } else if (EPI == 2) {
    float m2 = v * v;
    float z = v * fmaf(0.07135481627f, m2, 1.59576912161f);
    float e = __expf(z);
    float rr = __builtin_amdgcn_rcpf(e + 1.0f);
    ((bf16_t*)out0)[obase + gcol] = f2b(fmaf(-v, rr, v));
  } else {
    ((float*)out0)[obase + gcol] = v + extra[obase + gcol];
  }
}

// ---------------- gemmP: persistent 256x128 GEMM, reg-staged plain loads ------
// R7 change: NO global_load_lds.  Staging = plain global_load -> 4-slot reg
// queue (all indices compile-time: slot = step&3, NT%4==0) -> ds_write into a
// 2-deep LDS double buffer.  Rationale: every gld16 schedule (R0,R1,R3,R4,R6)
// pinned at ~1.5 TB/s chip / ~6 GB/s/CU fetch; R5's (broken) plain-load kernel
// pulled 3.5 TB/s HBM on the same tensors -> the gld16 path, not the schedule,
// is the cold-HBM bottleneck.
// Tile 256(M)x128(N), BK=32; 8 waves (4M x 2N), wave 64x64, acc[4][4] (AGPR).
// LDS 48 KB: A dbuf 2x16 KB + B dbuf 2x8 KB.  Per thread per step 48 B:
// A 32 B (row tid>>1, chunks (tid&1)*2+{0,1}), B 16 B (row tid>>2, chunk tid&3);
// ds_write address carries the proven XOR swizzle (write side), source linear.
// Per step ONE barrier: {frag ds_reads | issue loads s+3 | ds_write s+1 (compiler
// emits exact vmcnt) | lgkm(0) | setprio+16 MFMA | lgkm(0)+barrier}.
// Flat walk: XCD x owns tiles tau in [0,49*NBN); block j takes tau = j+32*t
// (bn = tau%NBN fastest -> consecutive co-running blocks share A panels in L2).
template<int EPI, int NBN>
__global__ __launch_bounds__(512, 2)
void gemmP(const bf16_t* __restrict__ A, const bf16_t* __restrict__ Bw,
           const float* __restrict__ bias, const float* __restrict__ extra,
           void* __restrict__ out0, void* __restrict__ out1v, void* __restrict__ out2v,
           const int K)
{
  __shared__ __align__(128) bf16_t ldsA[2][8192];   // [buf][256r x 32k]
  __shared__ __align__(128) bf16_t ldsB[2][4096];   // [buf][128r x 32k]
  const int tid = threadIdx.x, lane = tid & 63, wave = tid >> 6;
  const int NT = K >> 5;
  const int xcd = blockIdx.x & 7, j = blockIdx.x >> 3;
  const int m0 = xcd * 49;
  const int ntileX = 49 * NBN;
  const int tiles = (ntileX - j + 31) >> 5;       // ceil((ntileX-j)/32)

  // staging source (linear): A row tid>>1, 32 B; B row tid>>2, 16 B
  const int arow = tid >> 1, ac = (tid & 1) * 2;  // chunks ac, ac+1
  const int brow = tid >> 2, bc = tid & 3;
  // swizzled LDS write byte offsets (read side uses fkc ^ ((fr>>1)&3))
  const int awb0 = arow * 64 + ((ac ^ ((arow >> 1) & 3)) << 4);
  const int awb1 = arow * 64 + (((ac + 1) ^ ((arow >> 1) & 3)) << 4);
  const int bwb  = brow * 64 + ((bc ^ ((brow >> 1) & 3)) << 4);

  // staging cursors
  int ktS = 0, tS = j;
  const bf16_t* pA = A + ((size_t)(m0 + tS / NBN) * 256 + arow) * K + ac * 8;
  const bf16_t* pB = Bw + ((size_t)(tS % NBN) * 128 + brow) * K + bc * 8;
  uint4 qA0[4], qA1[4], qB[4];

#define ISSUE(SLOT) do { \
    qA0[SLOT] = *(const uint4*)(pA + ktS * 32); \
    qA1[SLOT] = *(const uint4*)(pA + ktS * 32 + 8); \
    qB[SLOT]  = *(const uint4*)(pB + ktS * 32); \
    if (++ktS == NT) { \
      ktS = 0; tS += 32; \
      if (tS < ntileX) { \
        pA = A + ((size_t)(m0 + tS / NBN) * 256 + arow) * K + ac * 8; \
        pB = Bw + ((size_t)(tS % NBN) * 128 + brow) * K + bc * 8; \
      } \
    } \
  } while (0)

#define COMMIT(SLOT, BUF) do { \
    *(uint4*)((char*)&ldsA[BUF][0] + awb0) = qA0[SLOT]; \
    *(uint4*)((char*)&ldsA[BUF][0] + awb1) = qA1[SLOT]; \
    *(uint4*)((char*)&ldsB[BUF][0] + bwb)  = qB[SLOT]; \
  } while (0)

  // fragment addressing: chunk fkc of row R lives at slot fkc ^ ((R>>1)&3);
  // (R>>1)&3 == (fr>>1)&3 for every fragment row.
  const int fr = lane & 15, fkc = lane >> 4;
  const int wr = wave >> 1, wc = wave & 1;
  const int slotq = (fkc ^ ((fr >> 1) & 3)) << 3;
  const int aoff = (wr * 64 + fr) * 32 + slotq;   // + m*512
  const int boff = (wc * 64 + fr) * 32 + slotq;   // + n*512

  f32x4 acc[4][4] = {};

  // prologue: issue steps 0,1,2 (slots 0,1,2); commit step 0 -> buf 0
  ISSUE(0); ISSUE(1); ISSUE(2);
  COMMIT(0, 0);
  asm volatile("s_waitcnt lgkmcnt(0)");
  __builtin_amdgcn_s_barrier();
  __builtin_amdgcn_sched_barrier(0);

  const int rq = fkc * 4;

  for (int t = 0; t < tiles; ++t) {
    const int tauC = j + t * 32;
    const int bmC = m0 + tauC / NBN;
    const int bnC = tauC % NBN;
#pragma unroll 4
    for (int kt = 0; kt < NT; ++kt) {
      // slot/buffer indices: global step s = t*NT+kt, NT%4==0 -> s&3 == kt&3
      bf16x8 af[4], bq[4];
#pragma unroll
      for (int m = 0; m < 4; ++m) af[m] = *(const bf16x8*)&ldsA[kt & 1][aoff + m * 512];
#pragma unroll
      for (int n = 0; n < 4; ++n) bq[n] = *(const bf16x8*)&ldsB[kt & 1][boff + n * 512];
      ISSUE((kt + 3) & 3);                       // loads for step s+3
      __builtin_amdgcn_sched_barrier(0);
      COMMIT((kt + 1) & 3, (kt + 1) & 1);        // compiler inserts exact vmcnt
      __builtin_amdgcn_sched_barrier(0);
      asm volatile("s_waitcnt lgkmcnt(0)");      // frags ready, writes committed
      __builtin_amdgcn_sched_barrier(0);
      __builtin_amdgcn_s_setprio(1);
#pragma unroll
      for (int m = 0; m < 4; ++m)
#pragma unroll
        for (int n = 0; n < 4; ++n)
          acc[m][n] = MFMA16(af[m], bq[n], acc[m][n]);
      __builtin_amdgcn_s_setprio(0);
      __builtin_amdgcn_sched_barrier(0);
      __builtin_amdgcn_s_barrier();
      __builtin_amdgcn_sched_barrier(0);
    }
    // ---- per-tile epilogue (queue keeps flying; compiler manages all waits)
    float bs[4];
#pragma unroll
    for (int n = 0; n < 4; ++n) bs[n] = bias[bnC * 128 + wc * 64 + n * 16 + fr];
#pragma unroll
    for (int m = 0; m < 4; ++m)
#pragma unroll
      for (int jj = 0; jj < 4; ++jj) {
        const int grow = bmC * 256 + wr * 64 + m * 16 + rq + jj;
#pragma unroll
        for (int n = 0; n < 4; ++n) {
          const int gcol = bnC * 128 + wc * 64 + n * 16 + fr;
          epi_store<EPI>(grow, gcol, acc[m][n][jj] + bs[n], extra, out0, out1v, out2v);
        }
      }
#pragma unroll
    for (int m = 0; m < 4; ++m)
#pragma unroll
      for (int n = 0; n < 4; ++n) acc[m][n] = (f32x4){0.f, 0.f, 0.f, 0.f};
  }
#undef ISSUE
#undef COMMIT
}

// ---------------- attention: one block per (window, head) ----------------
__global__ __launch_bounds__(256)
void attn_kernel(const bf16_t* __restrict__ qb, const bf16_t* __restrict__ kb,
                 const bf16_t* __restrict__ vb, const float* __restrict__ biasf,
                 bf16_t* __restrict__ aout)
{
  __shared__ bf16_t Q[64 * 32];
  __shared__ bf16_t Kl[64 * 32];
  __shared__ bf16_t Vt[32 * 64];
  __shared__ bf16_t Pl[4][16 * 64];
  const int bid = blockIdx.x;
  const int bw = bid >> 4, head = bid & 15;
  const int tid = threadIdx.x, lane = tid & 63, wave = tid >> 6;
  {
    uint4 z = {0u, 0u, 0u, 0u};
    *(uint4*)&Q[tid * 8] = z;
    *(uint4*)&Kl[tid * 8] = z;
    *(uint4*)&Vt[tid * 8] = z;
  }
  __syncthreads();
  const bf16_t* qsrc = qb + (long)bid * (49 * 32);
  const bf16_t* ksrc = kb + (long)bid * (49 * 32);
  const bf16_t* vsrc = vb + (long)bid * (49 * 32);
  if (tid < 196) {
    *(uint4*)&Q[tid * 8] = *(const uint4*)(qsrc + tid * 8);
    *(uint4*)&Kl[tid * 8] = *(const uint4*)(ksrc + tid * 8);
  }
  for (int e = tid; e < 1568; e += 256) {
    int t = e >> 5, d = e & 31;
    Vt[d * 64 + t] = vsrc[e];
  }
  __syncthreads();
  const int fr = lane & 15, fk = (lane >> 4) * 8, rq = (lane >> 4) * 4;
  bf16x8 aq = *(const bf16x8*)&Q[(wave * 16 + fr) * 32 + fk];
  f32x4 s[4];
#pragma unroll
  for (int n = 0; n < 4; ++n) {
    bf16x8 bk = *(const bf16x8*)&Kl[(n * 16 + fr) * 32 + fk];
    f32x4 z = {0.f, 0.f, 0.f, 0.f};
    s[n] = __builtin_amdgcn_mfma_f32_16x16x32_bf16(aq, bk, z, 0, 0, 0);
  }
  const int w = bw & 63;
  const bool wh7 = ((w >> 3) == 7), ww7 = ((w & 7) == 7);
  const float* bh = biasf + head * 4096;
#pragma unroll
  for (int j = 0; j < 4; ++j) {
    const int row = wave * 16 + rq + j;  // t1 in [0,64)
    int i1 = row / 7, j1 = row - i1 * 7;
    bool b1h = wh7 && (i1 >= 4), b1w = ww7 && (j1 >= 4);
    float pv[4];
    float mx = -3.0e38f;
#pragma unroll
    for (int n = 0; n < 4; ++n) {
      const int col = n * 16 + fr;
      float v = s[n][j] + bh[row * 64 + col];
      if (wh7 || ww7) {
        int i2 = col / 7, j2 = col - i2 * 7;
        bool b2h = wh7 && (i2 >= 4), b2w = ww7 && (j2 >= 4);
        if ((b1h != b2h) || (b1w != b2w)) v -= 100.f;
      }
      pv[n] = v;
      mx = fmaxf(mx, v);
    }
#pragma unroll
    for (int msk = 1; msk < 16; msk <<= 1) mx = fmaxf(mx, __shfl_xor(mx, msk));
    float sm = 0.f;
#pragma unroll
    for (int n = 0; n < 4; ++n) { pv[n] = __expf(pv[n] - mx); sm += pv[n]; }
#pragma unroll
    for (int msk = 1; msk < 16; msk <<= 1) sm += __shfl_xor(sm, msk);
    const float inv = 1.f / sm;
#pragma unroll
    for (int n = 0; n < 4; ++n)
      Pl[wave][(rq + j) * 64 + n * 16 + fr] = f2b(pv[n] * inv);
  }
  __syncthreads();
  f32x4 o[2] = {};
#pragma unroll
  for (int kk = 0; kk < 2; ++kk) {
    bf16x8 pa = *(const bf16x8*)&Pl[wave][fr * 64 + kk * 32 + fk];
#pragma unroll
    for (int dt = 0; dt < 2; ++dt) {
      bf16x8 vv = *(const bf16x8*)&Vt[(dt * 16 + fr) * 64 + kk * 32 + fk];
      o[dt] = __builtin_amdgcn_mfma_f32_16x16x32_bf16(pa, vv, o[dt], 0, 0, 0);
    }
  }
#pragma unroll
  for (int j = 0; j < 4; ++j) {
    const int t1 = wave * 16 + rq + j;
    if (t1 < 49) {
      bf16_t* dst = aout + ((long)bw * 49 + t1) * 512 + head * 32;
      dst[fr] = f2b(o[0][j]);
      dst[16 + fr] = f2b(o[1][j]);
    }
  }
}

// ---------------- launch ----------------
extern "C" void kernel_launch(void* const* d_in, const int* in_sizes, int n_in,
                              void* d_out, int out_size, void* d_ws, size_t ws_size,
                              hipStream_t stream)
{
  const float* x      = (const float*)d_in[0];
  const float* n1g    = (const float*)d_in[1];
  const float* n1b    = (const float*)d_in[2];
  const float* qkv_w  = (const float*)d_in[3];
  const float* qkv_b  = (const float*)d_in[4];
  const float* rel    = (const float*)d_in[5];
  const float* proj_w = (const float*)d_in[6];
  const float* proj_b = (const float*)d_in[7];
  const float* n2g    = (const float*)d_in[8];
  const float* n2b    = (const float*)d_in[9];
  const float* w1     = (const float*)d_in[10];
  const float* b1     = (const float*)d_in[11];
  const float* w2     = (const float*)d_in[12];
  const float* b2     = (const float*)d_in[13];

  char* ws = (char*)d_ws;
  bf16_t* Wqkv  = (bf16_t*)(ws + 0);          // 1536*512*2 = 1572864
  bf16_t* Wproj = (bf16_t*)(ws + 1572864);    // 512*512*2  = 524288
  bf16_t* Wm1   = (bf16_t*)(ws + 2097152);    // 2048*512*2 = 2097152
  bf16_t* Wm2   = (bf16_t*)(ws + 4194304);    // 512*2048*2 = 2097152
  float*  biasf = (float*)(ws + 6291456);     // 16*64*64*4 = 1048576
  const size_t ABYTES = (size_t)100352 * 512 * 2;  // 102760448
  const size_t P1 = 8388608;
  const size_t P2 = P1 + ABYTES + 1048576;         // 112197632
  bf16_t* xw      = (bf16_t*)(ws + P1);
  bf16_t* qbuf    = (bf16_t*)(ws + P2);
  bf16_t* kbuf    = (bf16_t*)(ws + P2 + ABYTES);
  bf16_t* vbuf    = (bf16_t*)(ws + P2 + 2 * ABYTES);
  bf16_t* attnout = xw;       // reuse after QKV gemm consumed xw
  bf16_t* h2      = xw;       // reuse after proj consumed attnout
  bf16_t* hidden  = qbuf;     // reuse q/k/v (+spare) after attention

  cvtw<<<768, 256, 0, stream>>>(qkv_w, Wqkv, 1536 * 512);
  cvtw<<<256, 256, 0, stream>>>(proj_w, Wproj, 512 * 512);
  cvtw<<<1024, 256, 0, stream>>>(w1, Wm1, 2048 * 512);
  cvtw<<<1024, 256, 0, stream>>>(w2, Wm2, 512 * 2048);
  bias_pre<<<256, 256, 0, stream>>>(rel, biasf);

  ln_kernel<true><<<100352, 128, 0, stream>>>(x, n1g, n1b, xw);
  gemmP<0, 12><<<256, 512, 0, stream>>>(xw, Wqkv, qkv_b, nullptr,
                                        qbuf, kbuf, vbuf, 512);
  attn_kernel<<<32768, 256, 0, stream>>>(qbuf, kbuf, vbuf, biasf, attnout);
  gemmP<1, 4><<<256, 512, 0, stream>>>(attnout, Wproj, proj_b, x,
                                       d_out, nullptr, nullptr, 512);
  ln_kernel<false><<<100352, 128, 0, stream>>>((const float*)d_out, n2g, n2b, h2);
  gemmP<2, 16><<<256, 512, 0, stream>>>(h2, Wm1, b1, nullptr,
                                        hidden, nullptr, nullptr, 512);
  gemmP<3, 4><<<256, 512, 0, stream>>>(hidden, Wm2, b2, (const float*)d_out,
                                       d_out, nullptr, nullptr, 2048);
}

// Round 8
// 1627.686 us; speedup vs baseline: 2.6423x; 2.6423x over previous
//
#include <hip/hip_runtime.h>
#include <cstdint>
#include <cstddef>

#define DI __device__ __forceinline__

typedef __bf16 bf16_t;
typedef __bf16 bf16x8 __attribute__((ext_vector_type(8)));
typedef float f32x4 __attribute__((ext_vector_type(4)));

static constexpr float SCALE = 0.17677669529663687f;  // 32^-0.5

DI bf16_t f2b(float f) {
  uint32_t u = __builtin_bit_cast(uint32_t, f);
  u += 0x7fffu + ((u >> 16) & 1u);
  return __builtin_bit_cast(bf16_t, (uint16_t)(u >> 16));
}

DI void gld16(const void* g, void* l) {
  __builtin_amdgcn_global_load_lds(
      (const __attribute__((address_space(1))) uint32_t*)g,
      (__attribute__((address_space(3))) uint32_t*)l, 16, 0, 0);
}

// ---------------- weight convert f32 -> bf16 ----------------
__global__ __launch_bounds__(256)
void cvtw(const float* __restrict__ in, bf16_t* __restrict__ out, int n) {
  int i = (blockIdx.x * 256 + threadIdx.x) * 4;
  if (i >= n) return;
  float4 v = *(const float4*)(in + i);
  ushort4 o;
  o.x = __builtin_bit_cast(uint16_t, f2b(v.x));
  o.y = __builtin_bit_cast(uint16_t, f2b(v.y));
  o.z = __builtin_bit_cast(uint16_t, f2b(v.z));
  o.w = __builtin_bit_cast(uint16_t, f2b(v.w));
  *(ushort4*)(out + i) = o;
}

// ---------------- rel-pos bias expand: [16][64][64], pad = -1e30 ----------------
__global__ __launch_bounds__(256)
void bias_pre(const float* __restrict__ rel, float* __restrict__ bf) {
  int idx = blockIdx.x * 256 + threadIdx.x;  // 65536
  int head = idx >> 12, t1 = (idx >> 6) & 63, t2 = idx & 63;
  float v = -1e30f;
  if (t1 < 49 && t2 < 49) {
    int i1 = t1 / 7, j1 = t1 - i1 * 7, i2 = t2 / 7, j2 = t2 - i2 * 7;
    v = rel[((i1 - i2 + 6) * 13 + (j1 - j2 + 6)) * 16 + head];
  }
  bf[idx] = v;
}

// ---------------- LayerNorm, 2 rows per block ----------------
template<bool WIN>
__global__ __launch_bounds__(256)
void ln_kernel(const float* __restrict__ in, const float* __restrict__ g,
               const float* __restrict__ be, bf16_t* __restrict__ out)
{
  const int tid = threadIdx.x;
  const int r = blockIdx.x * 2 + (tid >> 7);   // output row
  const int ti = tid & 127;
  long srow;
  if (WIN) {
    int bw = r / 49, t = r - bw * 49;
    int b = bw >> 6, w = bw & 63;
    int wh = w >> 3, ww = w & 7;
    int i = t / 7, j = t - i * 7;
    int hs = wh * 7 + i + 3; if (hs >= 56) hs -= 56;
    int wsr = ww * 7 + j + 3; if (wsr >= 56) wsr -= 56;
    srow = (long)b * 3136 + hs * 56 + wsr;
  } else {
    srow = r;
  }
  const float4 v = *(const float4*)(in + srow * 512 + ti * 4);
  float s = v.x + v.y + v.z + v.w;
  float sq = v.x * v.x + v.y * v.y + v.z * v.z + v.w * v.w;
#pragma unroll
  for (int m = 1; m < 64; m <<= 1) { s += __shfl_xor(s, m); sq += __shfl_xor(sq, m); }
  __shared__ float ls[4], lq[4];
  const int wv = tid >> 6;
  if ((tid & 63) == 0) { ls[wv] = s; lq[wv] = sq; }
  __syncthreads();
  const int rp = (tid >> 7) * 2;
  s = ls[rp] + ls[rp + 1]; sq = lq[rp] + lq[rp + 1];
  const float mean = s * (1.f / 512.f);
  const float rs = rsqrtf(sq * (1.f / 512.f) - mean * mean + 1e-5f);
  const float4 gg = *(const float4*)(g + ti * 4);
  const float4 bb = *(const float4*)(be + ti * 4);
  ushort4 o;
  o.x = __builtin_bit_cast(uint16_t, f2b((v.x - mean) * rs * gg.x + bb.x));
  o.y = __builtin_bit_cast(uint16_t, f2b((v.y - mean) * rs * gg.y + bb.y));
  o.z = __builtin_bit_cast(uint16_t, f2b((v.z - mean) * rs * gg.z + bb.z));
  o.w = __builtin_bit_cast(uint16_t, f2b((v.w - mean) * rs * gg.w + bb.w));
  *(ushort4*)(out + (long)r * 512 + ti * 4) = o;
}

#define MFMA16(a, b, c) __builtin_amdgcn_mfma_f32_16x16x32_bf16((a), (b), (c), 0, 0, 0)

// Common epilogue address/value logic (verified across R3-R7)
template<int EPI>
DI void epi_store(int grow, int gcol, float v, const float* extra,
                  void* out0, void* out1v, void* out2v)
{
  long obase = 0;
  if (EPI == 0) {
    int bwi = grow / 49, t_ = grow - bwi * 49;
    obase = ((long)bwi * 784 + t_) * 32;
  } else if (EPI == 1) {
    int bwi = grow / 49, t_ = grow - bwi * 49;
    int b = bwi >> 6, w = bwi & 63;
    int wh = w >> 3, ww = w & 7;
    int i = t_ / 7, jj = t_ - i * 7;
    int hs = wh * 7 + i + 3; if (hs >= 56) hs -= 56;
    int wsr = ww * 7 + jj + 3; if (wsr >= 56) wsr -= 56;
    obase = ((long)b * 3136 + hs * 56 + wsr) * 512;
  } else if (EPI == 2) {
    obase = (long)grow * 2048;
  } else {
    obase = (long)grow * 512;
  }
  if (EPI == 0) {
    int part = gcol >> 9, head = (gcol >> 5) & 15, d = gcol & 31;
    if (part == 0) v *= SCALE;
    bf16_t* dst = (bf16_t*)(part == 0 ? out0 : (part == 1 ? out1v : out2v));
    dst[obase + (long)head * 1568 + d] = f2b(v);
  } else if (EPI == 1) {
    ((float*)out0)[obase + gcol] = v + extra[obase + gcol];
  } else if (EPI == 2) {
    float m2 = v * v;
    float z = v * fmaf(0.07135481627f, m2, 1.59576912161f);
    float e = __expf(z);
    float rr = __builtin_amdgcn_rcpf(e + 1.0f);
    ((bf16_t*)out0)[obase + gcol] = f2b(fmaf(-v, rr, v));
  } else {
    ((float*)out0)[obase + gcol] = v + extra[obase + gcol];
  }
}

// ---------------- gemmM: persistent 256x256, MIXED staging -------------------
// A/B test isolating the staging MECHANISM (R6 geometry held fixed):
//   A (cold stream): plain global_load -> 4 NAMED reg slots (no arrays; slot
//     rotation via 4-phase macro, NT compile-time) -> swizzled ds_write into
//     a 2-deep LDS dbuf.
//   B (L2-resident): R6's proven gld16 into a 4-deep LDS buffer.
// Per step s: {12 frag ds_reads | issue A-loads + B-gld16 for s+3 | lgkm(0) |
// 32 MFMA (af in 2 halves of 4 to cap VGPR) | vmcnt(8) -> step s+1's 4 vmem
// ops landed | ds_write A[s+1] | lgkm(0) | barrier}.  Cursor CLAMPS (re-reads
// valid tile 0) past stream end so vmcnt counting stays uniform -- no tail
// special case.  8 waves (2M x 4N), wave 128x64, acc[8][4]; LDS 96 KB.
// Walk: XCD x owns 49*NBN tiles; block j (0..31) takes tau = j + 32*t
// (bn = tau%NBN fastest -> co-running blocks share A panels in L2).
template<int EPI, int NBN, int NT>
__global__ __launch_bounds__(512, 2)
void gemmM(const bf16_t* __restrict__ A, const bf16_t* __restrict__ Bw,
           const float* __restrict__ bias, const float* __restrict__ extra,
           void* __restrict__ out0, void* __restrict__ out1v, void* __restrict__ out2v)
{
  constexpr int K = NT * 32;
  __shared__ __align__(128) bf16_t ldsA[2][8192];   // 32 KB
  __shared__ __align__(128) bf16_t ldsB[4][8192];   // 64 KB
  const int tid = threadIdx.x, lane = tid & 63, wave = tid >> 6;
  const int xcd = blockIdx.x & 7, j = blockIdx.x >> 3;
  const int m0 = xcd * 49;
  constexpr int ntileX = 49 * NBN;
  const int tiles = (ntileX - j + 31) >> 5;

  // ---- A staging (reg path): thread covers row tid>>1, 32 B (2 chunks) ----
  const int arow = tid >> 1, ac = (tid & 1) * 2;
  const int awb0 = arow * 64 + ((ac ^ ((arow >> 1) & 3)) << 4);
  const int awb1 = arow * 64 + (((ac + 1) ^ ((arow >> 1) & 3)) << 4);
  // ---- B staging (gld16 path, R6-proven): rows bsrow, bsrow+128 ----
  const int bsrow = tid >> 2;
  const int bchunk = (tid & 3) ^ ((bsrow >> 1) & 3);

  // staging cursor
  int ktS = 0, tS = j;
  const bf16_t* pA = A + ((size_t)(m0 + tS / NBN) * 256 + arow) * K + ac * 8;
  const bf16_t* pB = Bw + ((size_t)(tS % NBN) * 256 + bsrow) * K + bchunk * 8;

  struct QA { uint4 x, y; };
  QA qa0, qa1, qa2, qa3;

#define ADV() do { \
    if (++ktS == NT) { \
      ktS = 0; tS += 32; if (tS >= ntileX) tS = j; \
      pA = A + ((size_t)(m0 + tS / NBN) * 256 + arow) * K + ac * 8; \
      pB = Bw + ((size_t)(tS % NBN) * 256 + bsrow) * K + bchunk * 8; \
    } \
  } while (0)

#define STEPOPS(QI, TGT) do { \
    QI.x = *(const uint4*)(pA + ktS * 32); \
    QI.y = *(const uint4*)(pA + ktS * 32 + 8); \
    gld16(pB + ktS * 32, &ldsB[TGT][tid * 8]); \
    gld16(pB + ktS * 32 + (size_t)128 * K, &ldsB[TGT][tid * 8 + 4096]); \
    ADV(); \
  } while (0)

#define COMMIT(QC, BUF) do { \
    *(uint4*)((char*)&ldsA[BUF][0] + awb0) = QC.x; \
    *(uint4*)((char*)&ldsA[BUF][0] + awb1) = QC.y; \
  } while (0)

  // fragment addressing (R6-proven): chunk fkc of row R at slot fkc^((R>>1)&3)
  const int fr = lane & 15, fkc = lane >> 4;
  const int wr = wave >> 2, wc = wave & 3;
  const int slotq = (fkc ^ ((fr >> 1) & 3)) << 3;
  const int aoff = (wr * 128 + fr) * 32 + slotq;  // + m*512
  const int boff = (wc * 64 + fr) * 32 + slotq;   // + n*512

  f32x4 acc[8][4] = {};

  // prologue: steps 0,1,2 issued (12 vmem ops); step0 landed; commit A0
  STEPOPS(qa0, 0); STEPOPS(qa1, 1); STEPOPS(qa2, 2);
  asm volatile("s_waitcnt vmcnt(8)");
  __builtin_amdgcn_sched_barrier(0);
  COMMIT(qa0, 0);
  asm volatile("s_waitcnt lgkmcnt(0)");
  __builtin_amdgcn_s_barrier();
  __builtin_amdgcn_sched_barrier(0);

#define PH(P, QI, QC) do { \
    bf16x8 bq0 = *(const bf16x8*)&ldsB[(P) & 3][boff]; \
    bf16x8 bq1 = *(const bf16x8*)&ldsB[(P) & 3][boff + 512]; \
    bf16x8 bq2 = *(const bf16x8*)&ldsB[(P) & 3][boff + 1024]; \
    bf16x8 bq3 = *(const bf16x8*)&ldsB[(P) & 3][boff + 1536]; \
    bf16x8 a0 = *(const bf16x8*)&ldsA[(P) & 1][aoff]; \
    bf16x8 a1 = *(const bf16x8*)&ldsA[(P) & 1][aoff + 512]; \
    bf16x8 a2 = *(const bf16x8*)&ldsA[(P) & 1][aoff + 1024]; \
    bf16x8 a3 = *(const bf16x8*)&ldsA[(P) & 1][aoff + 1536]; \
    STEPOPS(QI, ((P) + 3) & 3); \
    asm volatile("s_waitcnt lgkmcnt(0)"); \
    __builtin_amdgcn_sched_barrier(0); \
    __builtin_amdgcn_s_setprio(1); \
    acc[0][0] = MFMA16(a0, bq0, acc[0][0]); acc[0][1] = MFMA16(a0, bq1, acc[0][1]); \
    acc[0][2] = MFMA16(a0, bq2, acc[0][2]); acc[0][3] = MFMA16(a0, bq3, acc[0][3]); \
    acc[1][0] = MFMA16(a1, bq0, acc[1][0]); acc[1][1] = MFMA16(a1, bq1, acc[1][1]); \
    acc[1][2] = MFMA16(a1, bq2, acc[1][2]); acc[1][3] = MFMA16(a1, bq3, acc[1][3]); \
    acc[2][0] = MFMA16(a2, bq0, acc[2][0]); acc[2][1] = MFMA16(a2, bq1, acc[2][1]); \
    acc[2][2] = MFMA16(a2, bq2, acc[2][2]); acc[2][3] = MFMA16(a2, bq3, acc[2][3]); \
    acc[3][0] = MFMA16(a3, bq0, acc[3][0]); acc[3][1] = MFMA16(a3, bq1, acc[3][1]); \
    acc[3][2] = MFMA16(a3, bq2, acc[3][2]); acc[3][3] = MFMA16(a3, bq3, acc[3][3]); \
    a0 = *(const bf16x8*)&ldsA[(P) & 1][aoff + 2048]; \
    a1 = *(const bf16x8*)&ldsA[(P) & 1][aoff + 2560]; \
    a2 = *(const bf16x8*)&ldsA[(P) & 1][aoff + 3072]; \
    a3 = *(const bf16x8*)&ldsA[(P) & 1][aoff + 3584]; \
    asm volatile("s_waitcnt lgkmcnt(0)"); \
    __builtin_amdgcn_sched_barrier(0); \
    acc[4][0] = MFMA16(a0, bq0, acc[4][0]); acc[4][1] = MFMA16(a0, bq1, acc[4][1]); \
    acc[4][2] = MFMA16(a0, bq2, acc[4][2]); acc[4][3] = MFMA16(a0, bq3, acc[4][3]); \
    acc[5][0] = MFMA16(a1, bq0, acc[5][0]); acc[5][1] = MFMA16(a1, bq1, acc[5][1]); \
    acc[5][2] = MFMA16(a1, bq2, acc[5][2]); acc[5][3] = MFMA16(a1, bq3, acc[5][3]); \
    acc[6][0] = MFMA16(a2, bq0, acc[6][0]); acc[6][1] = MFMA16(a2, bq1, acc[6][1]); \
    acc[6][2] = MFMA16(a2, bq2, acc[6][2]); acc[6][3] = MFMA16(a2, bq3, acc[6][3]); \
    acc[7][0] = MFMA16(a3, bq0, acc[7][0]); acc[7][1] = MFMA16(a3, bq1, acc[7][1]); \
    acc[7][2] = MFMA16(a3, bq2, acc[7][2]); acc[7][3] = MFMA16(a3, bq3, acc[7][3]); \
    __builtin_amdgcn_s_setprio(0); \
    __builtin_amdgcn_sched_barrier(0); \
    asm volatile("s_waitcnt vmcnt(8)"); \
    __builtin_amdgcn_sched_barrier(0); \
    COMMIT(QC, ((P) + 1) & 1); \
    asm volatile("s_waitcnt lgkmcnt(0)"); \
    __builtin_amdgcn_s_barrier(); \
    __builtin_amdgcn_sched_barrier(0); \
  } while (0)

  const int rq = fkc * 4;

  for (int t = 0; t < tiles; ++t) {
    const int tauC = j + t * 32;
    const int bmC = m0 + tauC / NBN;
    const int bnC = tauC % NBN;
#pragma unroll 1
    for (int it = 0; it < NT / 4; ++it) {
      PH(0, qa3, qa1);
      PH(1, qa0, qa2);
      PH(2, qa1, qa3);
      PH(3, qa2, qa0);
    }
    // ---- per-tile epilogue (stores only tighten later vmcnt waits -- safe)
    float bs[4];
#pragma unroll
    for (int n = 0; n < 4; ++n) bs[n] = bias[bnC * 256 + wc * 64 + n * 16 + fr];
#pragma unroll
    for (int m = 0; m < 8; ++m)
#pragma unroll
      for (int jj = 0; jj < 4; ++jj) {
        const int grow = bmC * 256 + wr * 128 + m * 16 + rq + jj;
#pragma unroll
        for (int n = 0; n < 4; ++n) {
          const int gcol = bnC * 256 + wc * 64 + n * 16 + fr;
          epi_store<EPI>(grow, gcol, acc[m][n][jj] + bs[n], extra, out0, out1v, out2v);
        }
      }
#pragma unroll
    for (int m = 0; m < 8; ++m)
#pragma unroll
      for (int n = 0; n < 4; ++n) acc[m][n] = (f32x4){0.f, 0.f, 0.f, 0.f};
  }
#undef PH
#undef COMMIT
#undef STEPOPS
#undef ADV
}

// ---------------- attention: one block per (window, head) ----------------
__global__ __launch_bounds__(256)
void attn_kernel(const bf16_t* __restrict__ qb, const bf16_t* __restrict__ kb,
                 const bf16_t* __restrict__ vb, const float* __restrict__ biasf,
                 bf16_t* __restrict__ aout)
{
  __shared__ bf16_t Q[64 * 32];
  __shared__ bf16_t Kl[64 * 32];
  __shared__ bf16_t Vt[32 * 64];
  __shared__ bf16_t Pl[4][16 * 64];
  const int bid = blockIdx.x;
  const int bw = bid >> 4, head = bid & 15;
  const int tid = threadIdx.x, lane = tid & 63, wave = tid >> 6;
  {
    uint4 z = {0u, 0u, 0u, 0u};
    *(uint4*)&Q[tid * 8] = z;
    *(uint4*)&Kl[tid * 8] = z;
    *(uint4*)&Vt[tid * 8] = z;
  }
  __syncthreads();
  const bf16_t* qsrc = qb + (long)bid * (49 * 32);
  const bf16_t* ksrc = kb + (long)bid * (49 * 32);
  const bf16_t* vsrc = vb + (long)bid * (49 * 32);
  if (tid < 196) {
    *(uint4*)&Q[tid * 8] = *(const uint4*)(qsrc + tid * 8);
    *(uint4*)&Kl[tid * 8] = *(const uint4*)(ksrc + tid * 8);
  }
  for (int e = tid; e < 1568; e += 256) {
    int t = e >> 5, d = e & 31;
    Vt[d * 64 + t] = vsrc[e];
  }
  __syncthreads();
  const int fr = lane & 15, fk = (lane >> 4) * 8, rq = (lane >> 4) * 4;
  bf16x8 aq = *(const bf16x8*)&Q[(wave * 16 + fr) * 32 + fk];
  f32x4 s[4];
#pragma unroll
  for (int n = 0; n < 4; ++n) {
    bf16x8 bk = *(const bf16x8*)&Kl[(n * 16 + fr) * 32 + fk];
    f32x4 z = {0.f, 0.f, 0.f, 0.f};
    s[n] = __builtin_amdgcn_mfma_f32_16x16x32_bf16(aq, bk, z, 0, 0, 0);
  }
  const int w = bw & 63;
  const bool wh7 = ((w >> 3) == 7), ww7 = ((w & 7) == 7);
  const float* bh = biasf + head * 4096;
#pragma unroll
  for (int j = 0; j < 4; ++j) {
    const int row = wave * 16 + rq + j;  // t1 in [0,64)
    int i1 = row / 7, j1 = row - i1 * 7;
    bool b1h = wh7 && (i1 >= 4), b1w = ww7 && (j1 >= 4);
    float pv[4];
    float mx = -3.0e38f;
#pragma unroll
    for (int n = 0; n < 4; ++n) {
      const int col = n * 16 + fr;
      float v = s[n][j] + bh[row * 64 + col];
      if (wh7 || ww7) {
        int i2 = col / 7, j2 = col - i2 * 7;
        bool b2h = wh7 && (i2 >= 4), b2w = ww7 && (j2 >= 4);
        if ((b1h != b2h) || (b1w != b2w)) v -= 100.f;
      }
      pv[n] = v;
      mx = fmaxf(mx, v);
    }
#pragma unroll
    for (int msk = 1; msk < 16; msk <<= 1) mx = fmaxf(mx, __shfl_xor(mx, msk));
    float sm = 0.f;
#pragma unroll
    for (int n = 0; n < 4; ++n) { pv[n] = __expf(pv[n] - mx); sm += pv[n]; }
#pragma unroll
    for (int msk = 1; msk < 16; msk <<= 1) sm += __shfl_xor(sm, msk);
    const float inv = 1.f / sm;
#pragma unroll
    for (int n = 0; n < 4; ++n)
      Pl[wave][(rq + j) * 64 + n * 16 + fr] = f2b(pv[n] * inv);
  }
  __syncthreads();
  f32x4 o[2] = {};
#pragma unroll
  for (int kk = 0; kk < 2; ++kk) {
    bf16x8 pa = *(const bf16x8*)&Pl[wave][fr * 64 + kk * 32 + fk];
#pragma unroll
    for (int dt = 0; dt < 2; ++dt) {
      bf16x8 vv = *(const bf16x8*)&Vt[(dt * 16 + fr) * 64 + kk * 32 + fk];
      o[dt] = __builtin_amdgcn_mfma_f32_16x16x32_bf16(pa, vv, o[dt], 0, 0, 0);
    }
  }
#pragma unroll
  for (int j = 0; j < 4; ++j) {
    const int t1 = wave * 16 + rq + j;
    if (t1 < 49) {
      bf16_t* dst = aout + ((long)bw * 49 + t1) * 512 + head * 32;
      dst[fr] = f2b(o[0][j]);
      dst[16 + fr] = f2b(o[1][j]);
    }
  }
}

// ---------------- launch ----------------
extern "C" void kernel_launch(void* const* d_in, const int* in_sizes, int n_in,
                              void* d_out, int out_size, void* d_ws, size_t ws_size,
                              hipStream_t stream)
{
  const float* x      = (const float*)d_in[0];
  const float* n1g    = (const float*)d_in[1];
  const float* n1b    = (const float*)d_in[2];
  const float* qkv_w  = (const float*)d_in[3];
  const float* qkv_b  = (const float*)d_in[4];
  const float* rel    = (const float*)d_in[5];
  const float* proj_w = (const float*)d_in[6];
  const float* proj_b = (const float*)d_in[7];
  const float* n2g    = (const float*)d_in[8];
  const float* n2b    = (const float*)d_in[9];
  const float* w1     = (const float*)d_in[10];
  const float* b1     = (const float*)d_in[11];
  const float* w2     = (const float*)d_in[12];
  const float* b2     = (const float*)d_in[13];

  char* ws = (char*)d_ws;
  bf16_t* Wqkv  = (bf16_t*)(ws + 0);          // 1536*512*2 = 1572864
  bf16_t* Wproj = (bf16_t*)(ws + 1572864);    // 512*512*2  = 524288
  bf16_t* Wm1   = (bf16_t*)(ws + 2097152);    // 2048*512*2 = 2097152
  bf16_t* Wm2   = (bf16_t*)(ws + 4194304);    // 512*2048*2 = 2097152
  float*  biasf = (float*)(ws + 6291456);     // 16*64*64*4 = 1048576
  const size_t ABYTES = (size_t)100352 * 512 * 2;  // 102760448
  const size_t P1 = 8388608;
  const size_t P2 = P1 + ABYTES + 1048576;         // 112197632
  bf16_t* xw      = (bf16_t*)(ws + P1);
  bf16_t* qbuf    = (bf16_t*)(ws + P2);
  bf16_t* kbuf    = (bf16_t*)(ws + P2 + ABYTES);
  bf16_t* vbuf    = (bf16_t*)(ws + P2 + 2 * ABYTES);
  bf16_t* attnout = xw;       // reuse after QKV gemm consumed xw
  bf16_t* h2      = xw;       // reuse after proj consumed attnout
  bf16_t* hidden  = qbuf;     // reuse q/k/v (+spare) after attention

  cvtw<<<768, 256, 0, stream>>>(qkv_w, Wqkv, 1536 * 512);
  cvtw<<<256, 256, 0, stream>>>(proj_w, Wproj, 512 * 512);
  cvtw<<<1024, 256, 0, stream>>>(w1, Wm1, 2048 * 512);
  cvtw<<<1024, 256, 0, stream>>>(w2, Wm2, 512 * 2048);
  bias_pre<<<256, 256, 0, stream>>>(rel, biasf);

  ln_kernel<true><<<50176, 256, 0, stream>>>(x, n1g, n1b, xw);
  gemmM<0, 6, 16><<<256, 512, 0, stream>>>(xw, Wqkv, qkv_b, nullptr,
                                           qbuf, kbuf, vbuf);
  attn_kernel<<<32768, 256, 0, stream>>>(qbuf, kbuf, vbuf, biasf, attnout);
  gemmM<1, 2, 16><<<256, 512, 0, stream>>>(attnout, Wproj, proj_b, x,
                                           d_out, nullptr, nullptr);
  ln_kernel<false><<<50176, 256, 0, stream>>>((const float*)d_out, n2g, n2b, h2);
  gemmM<2, 8, 16><<<256, 512, 0, stream>>>(h2, Wm1, b1, nullptr,
                                           hidden, nullptr, nullptr);
  gemmM<3, 2, 64><<<256, 512, 0, stream>>>(hidden, Wm2, b2, (const float*)d_out,
                                           d_out, nullptr, nullptr);
}